// Round 1
// baseline (47.764 us; speedup 1.0000x reference)
//
#include <hip/hip_runtime.h>
#include <math.h>

// Gaussian splat forward: N gaussians -> res x res image.
// Stage 1: per-gaussian prep (quat->R, cov3d, project, invert, bbox).
// Stage 2: per 16x16 pixel tile, accumulate sum_n op_n * exp(quadform_n(dx,dy)).
//
// Inner-loop constants are pre-scaled by -0.5*log2(e) so the pixel loop is:
//   w = exp2(A*dx*dx + B*dy*dy + C*dx*dy)   -> single v_exp_f32
//
// Tile mask (reference TILE=16) is block-uniform -> folded into op_eff, with a
// uniform skip branch.

#define TILE 16
#define GCHUNK 256

__global__ __launch_bounds__(256) void gs_precompute(
    const float* __restrict__ xyz, const float* __restrict__ scaling,
    const float* __restrict__ rotation, const float* __restrict__ opacity,
    const float* __restrict__ rot,
    float4* __restrict__ P0, float4* __restrict__ P1, float4* __restrict__ P2,
    int N, float resf)
{
    int n = blockIdx.x * blockDim.x + threadIdx.x;
    if (n >= N) return;

    // quaternion -> rotation matrix (reference normalizes first)
    float qr = rotation[4*n+0], qx = rotation[4*n+1];
    float qy = rotation[4*n+2], qz = rotation[4*n+3];
    float inv = 1.0f / sqrtf(qr*qr + qx*qx + qy*qy + qz*qz);
    float r = qr*inv, x = qx*inv, y = qy*inv, z = qz*inv;

    float R00 = 1.f - 2.f*(y*y + z*z), R01 = 2.f*(x*y - r*z), R02 = 2.f*(x*z + r*y);
    float R10 = 2.f*(x*y + r*z), R11 = 1.f - 2.f*(x*x + z*z), R12 = 2.f*(y*z - r*x);
    float R20 = 2.f*(x*z - r*y), R21 = 2.f*(y*z + r*x), R22 = 1.f - 2.f*(x*x + y*y);

    // L = R * diag(s)  (column scaling)
    float s0 = scaling[3*n+0], s1 = scaling[3*n+1], s2 = scaling[3*n+2];
    float L00 = R00*s0, L01 = R01*s1, L02 = R02*s2;
    float L10 = R10*s0, L11 = R11*s1, L12 = R12*s2;
    float L20 = R20*s0, L21 = R21*s1, L22 = R22*s2;

    // A = diag(res,res,0) @ rot -> only rows 0,1 matter. cov2d = (A L)(A L)^T.
    float a00 = resf*rot[0], a01 = resf*rot[1], a02 = resf*rot[2];
    float a10 = resf*rot[3], a11 = resf*rot[4], a12 = resf*rot[5];
    float b00 = a00*L00 + a01*L10 + a02*L20;
    float b01 = a00*L01 + a01*L11 + a02*L21;
    float b02 = a00*L02 + a01*L12 + a02*L22;
    float b10 = a10*L00 + a11*L10 + a12*L20;
    float b11 = a10*L01 + a11*L11 + a12*L21;
    float b12 = a10*L02 + a11*L12 + a12*L22;
    float c00 = b00*b00 + b01*b01 + b02*b02;
    float c01 = b00*b10 + b01*b11 + b02*b12;   // == c10
    float c11 = b10*b10 + b11*b11 + b12*b12;

    float det = c00*c11 - c01*c01;
    float mid = 0.5f*(c00 + c11);
    float sq  = sqrtf(fmaxf(mid*mid - det, 0.1f));
    float lam = fmaxf(mid + sq, mid - sq);
    float radii = ceilf(3.0f * sqrtf(lam));

    float mx = xyz[3*n+0] * (resf*0.5f);
    float my = xyz[3*n+1] * (resf*0.5f);
    float rminx = fminf(fmaxf(mx - radii, 0.f), resf - 1.f);
    float rmaxx = fminf(fmaxf(mx + radii, 0.f), resf - 1.f);
    float rminy = fminf(fmaxf(my - radii, 0.f), resf - 1.f);
    float rmaxy = fminf(fmaxf(my + radii, 0.f), resf - 1.f);

    // power(ln) = -0.5*(dx^2*i00 + dy^2*i11 + dx*dy*(i01+i10)),
    //   i00=c11*idet, i11=c00*idet, i01+i10=-2*c01*idet
    // fold -0.5 and log2(e) so inner loop uses exp2 directly.
    float idet = 1.0f / det;
    const float L2E = 1.44269504088896340736f;
    float Ac = -0.5f * L2E * c11 * idet;
    float Bc = -0.5f * L2E * c00 * idet;
    float Cc =         L2E * c01 * idet;

    P0[n] = make_float4(mx, my, Ac, Bc);
    P1[n] = make_float4(Cc, opacity[n], 0.f, 0.f);
    P2[n] = make_float4(rminx, rmaxx, rminy, rmaxy);
}

__global__ __launch_bounds__(256) void gs_raster(
    const float4* __restrict__ P0, const float4* __restrict__ P1,
    const float4* __restrict__ P2, float* __restrict__ out,
    int N, int res, int nt)
{
    __shared__ float4 sP[GCHUNK];   // mx, my, A, B
    __shared__ float2 sQ[GCHUNK];   // C, op_eff (0 if tile-masked)

    int tid = threadIdx.x;
    int tX = blockIdx.x % nt, tY = blockIdx.x / nt;
    float tx0 = (float)(tX * TILE), tx1 = tx0 + (float)(TILE - 1);
    float ty0 = (float)(tY * TILE), ty1 = ty0 + (float)(TILE - 1);

    // stage one gaussian per thread, folding the tile mask into op_eff
    int g = blockIdx.y * GCHUNK + tid;
    float4 p0 = make_float4(0.f, 0.f, 0.f, 0.f);
    float Cc = 0.f, opEff = 0.f;
    if (g < N) {
        p0 = P0[g];
        float4 p1 = P1[g];
        float4 rc = P2[g];
        bool m = (fminf(rc.y, tx1) > fmaxf(rc.x, tx0)) &&
                 (fminf(rc.w, ty1) > fmaxf(rc.z, ty0));
        Cc = p1.x;
        opEff = m ? p1.y : 0.f;
    }
    sP[tid] = p0;
    sQ[tid] = make_float2(Cc, opEff);
    __syncthreads();

    int pxi = tX * TILE + (tid & (TILE - 1));
    int pyi = tY * TILE + (tid >> 4);  // TILE==16
    float px = (float)pxi - ((float)res * 0.5f - 0.5f);
    float py = (float)pyi - ((float)res * 0.5f - 0.5f);

    float acc = 0.f;
    #pragma unroll 4
    for (int i = 0; i < GCHUNK; ++i) {
        float2 q = sQ[i];
        if (q.y != 0.f) {            // block-uniform branch
            float4 p = sP[i];
            float dx = px - p.x;
            float dy = py - p.y;
            float pw = fmaf(dx*dx, p.z, fmaf(dy*dy, p.w, (dx*dy)*q.x));
            acc = fmaf(q.y, exp2f(pw), acc);
        }
    }
    atomicAdd(&out[pyi * res + pxi], acc);
}

extern "C" void kernel_launch(void* const* d_in, const int* in_sizes, int n_in,
                              void* d_out, int out_size, void* d_ws, size_t ws_size,
                              hipStream_t stream) {
    const float* xyz      = (const float*)d_in[0];
    const float* scaling  = (const float*)d_in[1];
    const float* rotation = (const float*)d_in[2];
    const float* opacity  = (const float*)d_in[3];
    const float* rot      = (const float*)d_in[4];
    // d_in[5] is res on device; derive host-side from out_size (res*res*1)
    int N   = in_sizes[0] / 3;
    int res = (int)(sqrt((double)out_size) + 0.5);
    int nt  = res / TILE;

    float4* P0 = (float4*)d_ws;
    float4* P1 = P0 + N;
    float4* P2 = P1 + N;
    float*  out = (float*)d_out;

    hipMemsetAsync(d_out, 0, (size_t)out_size * sizeof(float), stream);

    int pblocks = (N + 255) / 256;
    gs_precompute<<<pblocks, 256, 0, stream>>>(xyz, scaling, rotation, opacity,
                                               rot, P0, P1, P2, N, (float)res);

    int ks = (N + GCHUNK - 1) / GCHUNK;
    gs_raster<<<dim3(nt * nt, ks), 256, 0, stream>>>(P0, P1, P2, out, N, res, nt);
}

// Round 2
// 26.826 us; speedup vs baseline: 1.7805x; 1.7805x over previous
//
#include <hip/hip_runtime.h>
#include <math.h>

// Gaussian splat forward: N gaussians -> res x res image.
//
// Stage 1 (gs_precompute, 1024 threads): per-gaussian quat->R, cov3d, project,
// invert, bbox; then EXPAND the quadratic form about the pixel basis:
//   pw*log2e = c0*px^2 + c1*py^2 + c2*px*py + c3*px + c4*py + c5
// with log2(opacity) folded into c5, so the raster inner loop is
//   acc += exp2(5-term fma chain)            -- branchless, 7 VALU/pair.
//
// Stage 2 (gs_raster): one block per 16x16 pixel tile x gaussian-chunk of 128.
// Tile mask (block-uniform) folded into c5 as -inf at LDS staging time.
// 2048 blocks -> 8 blocks/CU -> 32 waves/CU for latency hiding.

#define TILE 16
#define GCHUNK 128

__global__ __launch_bounds__(256) void gs_precompute(
    const float* __restrict__ xyz, const float* __restrict__ scaling,
    const float* __restrict__ rotation, const float* __restrict__ opacity,
    const float* __restrict__ rot,
    float4* __restrict__ C4, float2* __restrict__ C2, float4* __restrict__ RC,
    int N, float resf)
{
    int n = blockIdx.x * blockDim.x + threadIdx.x;
    if (n >= N) return;

    // quaternion -> rotation matrix (reference normalizes first)
    float qr = rotation[4*n+0], qx = rotation[4*n+1];
    float qy = rotation[4*n+2], qz = rotation[4*n+3];
    float inv = 1.0f / sqrtf(qr*qr + qx*qx + qy*qy + qz*qz);
    float r = qr*inv, x = qx*inv, y = qy*inv, z = qz*inv;

    float R00 = 1.f - 2.f*(y*y + z*z), R01 = 2.f*(x*y - r*z), R02 = 2.f*(x*z + r*y);
    float R10 = 2.f*(x*y + r*z), R11 = 1.f - 2.f*(x*x + z*z), R12 = 2.f*(y*z - r*x);
    float R20 = 2.f*(x*z - r*y), R21 = 2.f*(y*z + r*x), R22 = 1.f - 2.f*(x*x + y*y);

    // L = R * diag(s)
    float s0 = scaling[3*n+0], s1 = scaling[3*n+1], s2 = scaling[3*n+2];
    float L00 = R00*s0, L01 = R01*s1, L02 = R02*s2;
    float L10 = R10*s0, L11 = R11*s1, L12 = R12*s2;
    float L20 = R20*s0, L21 = R21*s1, L22 = R22*s2;

    // A = diag(res,res,0) @ rot -> rows 0,1. cov2d = (A L)(A L)^T.
    float a00 = resf*rot[0], a01 = resf*rot[1], a02 = resf*rot[2];
    float a10 = resf*rot[3], a11 = resf*rot[4], a12 = resf*rot[5];
    float b00 = a00*L00 + a01*L10 + a02*L20;
    float b01 = a00*L01 + a01*L11 + a02*L21;
    float b02 = a00*L02 + a01*L12 + a02*L22;
    float b10 = a10*L00 + a11*L10 + a12*L20;
    float b11 = a10*L01 + a11*L11 + a12*L21;
    float b12 = a10*L02 + a11*L12 + a12*L22;
    float c00 = b00*b00 + b01*b01 + b02*b02;
    float c01 = b00*b10 + b01*b11 + b02*b12;   // == c10
    float c11 = b10*b10 + b11*b11 + b12*b12;

    float det = c00*c11 - c01*c01;
    float mid = 0.5f*(c00 + c11);
    float sq  = sqrtf(fmaxf(mid*mid - det, 0.1f));
    float lam = fmaxf(mid + sq, mid - sq);
    float radii = ceilf(3.0f * sqrtf(lam));

    float mx = xyz[3*n+0] * (resf*0.5f);
    float my = xyz[3*n+1] * (resf*0.5f);
    float rminx = fminf(fmaxf(mx - radii, 0.f), resf - 1.f);
    float rmaxx = fminf(fmaxf(mx + radii, 0.f), resf - 1.f);
    float rminy = fminf(fmaxf(my - radii, 0.f), resf - 1.f);
    float rmaxy = fminf(fmaxf(my + radii, 0.f), resf - 1.f);

    // quadform coefficients, pre-scaled by -0.5*log2(e):
    //   pw2 = A*dx^2 + B*dy^2 + Cc*dx*dy,  dx = px-mx, dy = py-my
    float idet = 1.0f / det;
    const float L2E = 1.44269504088896340736f;
    float A  = -0.5f * L2E * c11 * idet;
    float B  = -0.5f * L2E * c00 * idet;
    float Cc =         L2E * c01 * idet;

    // expand about (px,py):
    float c3 = -2.f*A*mx - Cc*my;
    float c4 = -2.f*B*my - Cc*mx;
    float c5 = A*mx*mx + B*my*my + Cc*mx*my + log2f(opacity[n]);

    C4[n] = make_float4(A, B, Cc, c3);
    C2[n] = make_float2(c4, c5);
    RC[n] = make_float4(rminx, rmaxx, rminy, rmaxy);
}

__global__ __launch_bounds__(256) void gs_raster(
    const float4* __restrict__ C4, const float2* __restrict__ C2,
    const float4* __restrict__ RC, float* __restrict__ out,
    int N, int res, int nt)
{
    __shared__ float4 sA[GCHUNK];   // c0,c1,c2,c3
    __shared__ float2 sB[GCHUNK];   // c4, c5_eff (-inf if tile-masked)

    int tid = threadIdx.x;
    int tX = blockIdx.x % nt, tY = blockIdx.x / nt;

    if (tid < GCHUNK) {
        int g = blockIdx.y * GCHUNK + tid;
        float4 a = make_float4(0.f, 0.f, 0.f, 0.f);
        float2 b = make_float2(0.f, -INFINITY);
        if (g < N) {
            a = C4[g];
            float2 c = C2[g];
            float4 rc = RC[g];
            float tx0 = (float)(tX * TILE), tx1 = tx0 + (float)(TILE - 1);
            float ty0 = (float)(tY * TILE), ty1 = ty0 + (float)(TILE - 1);
            bool m = (fminf(rc.y, tx1) > fmaxf(rc.x, tx0)) &&
                     (fminf(rc.w, ty1) > fmaxf(rc.z, ty0));
            b = make_float2(c.x, m ? c.y : -INFINITY);
        }
        sA[tid] = a;
        sB[tid] = b;
    }
    __syncthreads();

    int pxi = tX * TILE + (tid & (TILE - 1));
    int pyi = tY * TILE + (tid >> 4);  // TILE==16
    float X = (float)pxi - ((float)res * 0.5f - 0.5f);
    float Y = (float)pyi - ((float)res * 0.5f - 0.5f);
    float X2 = X * X, Y2 = Y * Y, XY = X * Y;

    float acc0 = 0.f, acc1 = 0.f;
    #pragma unroll 4
    for (int i = 0; i < GCHUNK; i += 2) {
        float4 a0 = sA[i];     float2 b0 = sB[i];
        float4 a1 = sA[i + 1]; float2 b1 = sB[i + 1];
        float p0 = fmaf(a0.x, X2, fmaf(a0.y, Y2, fmaf(a0.z, XY,
                   fmaf(a0.w, X, fmaf(b0.x, Y, b0.y)))));
        float p1 = fmaf(a1.x, X2, fmaf(a1.y, Y2, fmaf(a1.z, XY,
                   fmaf(a1.w, X, fmaf(b1.x, Y, b1.y)))));
        acc0 += __builtin_amdgcn_exp2f(p0);
        acc1 += __builtin_amdgcn_exp2f(p1);
    }
    atomicAdd(&out[pyi * res + pxi], acc0 + acc1);
}

extern "C" void kernel_launch(void* const* d_in, const int* in_sizes, int n_in,
                              void* d_out, int out_size, void* d_ws, size_t ws_size,
                              hipStream_t stream) {
    const float* xyz      = (const float*)d_in[0];
    const float* scaling  = (const float*)d_in[1];
    const float* rotation = (const float*)d_in[2];
    const float* opacity  = (const float*)d_in[3];
    const float* rot      = (const float*)d_in[4];
    int N   = in_sizes[0] / 3;
    int res = (int)(sqrt((double)out_size) + 0.5);
    int nt  = res / TILE;

    float4* C4 = (float4*)d_ws;
    float2* C2 = (float2*)(C4 + N);
    float4* RC = (float4*)(C2 + N);
    float*  out = (float*)d_out;

    hipMemsetAsync(d_out, 0, (size_t)out_size * sizeof(float), stream);

    int pblocks = (N + 255) / 256;
    gs_precompute<<<pblocks, 256, 0, stream>>>(xyz, scaling, rotation, opacity,
                                               rot, C4, C2, RC, N, (float)res);

    int ks = (N + GCHUNK - 1) / GCHUNK;
    gs_raster<<<dim3(nt * nt, ks), 256, 0, stream>>>(C4, C2, RC, out, N, res, nt);
}